// Round 19
// baseline (276.383 us; speedup 1.0000x reference)
//
#include <hip/hip_runtime.h>
#include <hip/hip_bf16.h>
#include <stdint.h>

#define NPTS 131072
#define DIM  512
#define KC   512
#define BM   32
#define NKT  16          // DIM / 32

typedef float f32x16 __attribute__((ext_vector_type(16)));
typedef float f32x4  __attribute__((ext_vector_type(4)));
typedef short bf16x8 __attribute__((ext_vector_type(8)));

__device__ __forceinline__ float sq4(f32x4 a) {
  return a.x*a.x + a.y*a.y + a.z*a.z + a.w*a.w;
}

// packed RNE fp32->bf16 (v_cvt_pk_bf16_f32)
__device__ __forceinline__ bf16x8 pack8c(f32x4 a, f32x4 b) {
  union { __hip_bfloat162 h; short s[2]; } u0, u1, u2, u3;
  u0.h = __float22bfloat162_rn(make_float2(a.x, a.y));
  u1.h = __float22bfloat162_rn(make_float2(a.z, a.w));
  u2.h = __float22bfloat162_rn(make_float2(b.x, b.y));
  u3.h = __float22bfloat162_rn(make_float2(b.z, b.w));
  bf16x8 r;
  r[0] = u0.s[0]; r[1] = u0.s[1]; r[2] = u1.s[0]; r[3] = u1.s[1];
  r[4] = u2.s[0]; r[5] = u2.s[1]; r[6] = u3.s[0]; r[7] = u3.s[1];
  return r;
}

// scalar RNE (cluster pre-kernel only)
__device__ __forceinline__ short f2bf(float f) {
  union { float f; unsigned u; } v; v.f = f;
  unsigned r = v.u + 0x7FFFu + ((v.u >> 16) & 1u);
  return (short)(r >> 16);
}
__device__ __forceinline__ bf16x8 pack8(f32x4 a, f32x4 b) {
  bf16x8 p;
  p[0] = f2bf(a.x); p[1] = f2bf(a.y); p[2] = f2bf(a.z); p[3] = f2bf(a.w);
  p[4] = f2bf(b.x); p[5] = f2bf(b.y); p[6] = f2bf(b.z); p[7] = f2bf(b.w);
  return p;
}

// ---------------------------------------------------------------------------
// Cluster pre-kernel (verified R5-R18): fp32 [512][512] -> bf16 in MFMA-B-
// fragment order. Short offset = q*8192 + wn*2048 + nt*512 + (h*32+r)*8,
// q = k/16. Per (q,wn,nt) one wave reads a contiguous 1 KB fragment.
// c2[n] = ||c_n||^2 fp32.
// ---------------------------------------------------------------------------
__global__ void dec_pack(const float* __restrict__ C, short* __restrict__ Bp,
                         float* __restrict__ c2) {
  const int n    = blockIdx.x;
  const int lane = threadIdx.x;
  const float* src = C + (size_t)n * DIM + lane * 8;
  f32x4 v0 = *(const f32x4*)src;
  f32x4 v1 = *(const f32x4*)(src + 4);
  float s = sq4(v0) + sq4(v1);
  #pragma unroll
  for (int m = 1; m < 64; m <<= 1) s += __shfl_xor(s, m, 64);
  if (lane == 0) c2[n] = s;
  const int kt = lane >> 2;
  const int st = (lane >> 1) & 1;
  const int hh = lane & 1;
  const int wn = n >> 7, nt = (n >> 5) & 3, r = n & 31;
  const size_t slot =
      (((size_t)(kt * 2 + st) * 4 + wn) * 4 + nt) * 64 + hh * 32 + r;
  *(bf16x8*)(Bp + slot * 8) = pack8(v0, v1);
}

// ---------------------------------------------------------------------------
// Pass 1 (verified R9): X fp32 [131072][512] -> Xp bf16 in MFMA-A-fragment
// order + x2g[row] = ||x_row||^2 (exact fp32).
// Xp[(g*32+ks)*512 + lane*8 ..] holds X[g*32+r][ks*16+h*8+j] for
// lane = h*32+r — each (g,ks) slab is the literal 1 KB A-fragment.
// Reads sector-perfect (h-pair covers a full 64B sector); writes 1 KB
// contiguous per wave-instruction. 1024 blocks x 256 threads.
// ---------------------------------------------------------------------------
__global__ __launch_bounds__(256)
void dec_packx(const float* __restrict__ X, short* __restrict__ Xp,
               float* __restrict__ x2g) {
  const int g    = blockIdx.x * 4 + (threadIdx.x >> 6);
  const int lane = threadIdx.x & 63;
  const int h    = lane >> 5;
  const int r    = lane & 31;
  const float* src = X + (size_t)(g * 32 + r) * DIM + h * 8;
  short* dst = Xp + (size_t)g * 16384 + lane * 8;
  float x2 = 0.f;
  #pragma unroll 4
  for (int ks = 0; ks < 32; ++ks) {
    f32x4 lo = *(const f32x4*)(src + ks * 16);
    f32x4 hi = *(const f32x4*)(src + ks * 16 + 4);
    x2 += sq4(lo) + sq4(hi);
    *(bf16x8*)(dst + ks * 512) = pack8c(lo, hi);
  }
  x2 += __shfl_xor(x2, 32, 64);       // combine the two k-halves of the row
  if (lane < 32) x2g[g * 32 + r] = x2;
}

// ---------------------------------------------------------------------------
// Pass 2 (R19): pure register-fed GEMM — NO LDS, NO barriers, NO cvt,
// NO x2 in the loop; BOTH operands ping-pong prefetched one full kt ahead.
// 256 threads = 4 waves (wn = wave); block tile 32 x 512 (full cluster
// width -> block-local normalization); wave tile 32 x 128,
// 8 x mfma_f32_32x32x16_bf16 per kt, acc = 4 x f32x16 (64 AGPR).
//
// Per kt (fully unrolled; static ping-pong indices per rule #20):
//   issue A(kt+1) 2 loads (1 KB contiguous each, HBM/L3 Xp stream) then
//   B(kt+1) 8 loads (1 KB contiguous each, L2-resident Bp) into set
//   (kt+1)&1; then 8 MFMA on set kt&1 (loads a full kt old — latency
//   covered by the iteration + 12 staggered waves/CU of TLP; issue order
//   matches consume order so in-order vmcnt retirement never waits on
//   fresh loads). Waves fully independent -> pipe usage mixes instead of
//   the lockstep serialization that pinned single-pass at ~172 us.
// ~160 unified regs -> 3 waves/SIMD, 3 independent blocks/CU.
// Epilogue: x2g/c2 precomputed; q = rcp(1+d2); butterfly row-sums; one
// barrier; normalize; coalesced stores.
// ---------------------------------------------------------------------------
__global__ __launch_bounds__(256, 3)
void dec_main2(const short* __restrict__ Xp, const short* __restrict__ Bp,
               const float* __restrict__ c2g, const float* __restrict__ x2g,
               float* __restrict__ out) {
  __shared__ float part[4][BM];
  __shared__ float rowinv[BM];

  const int tid  = threadIdx.x;
  const int lane = tid & 63;
  const int wn   = tid >> 6;    // 0..3 : column quarter (one wave each)
  const int l31  = lane & 31;
  const int h    = lane >> 5;
  const int row0 = blockIdx.x * BM;

  const short* aB = Xp + (size_t)blockIdx.x * 16384 + lane * 8; // + kt*1024 + s*512
  const short* bB = Bp + wn * 2048 + lane * 8;      // + kt*16384 + s*8192 + nt*512

  f32x16 acc[4];
  #pragma unroll
  for (int nt = 0; nt < 4; ++nt) acc[nt] = (f32x16)0.f;

  bf16x8 aA[2], aS[2];          // A ping-pong: even kt in aA, odd in aS
  bf16x8 bA[2][4], bS[2][4];    // B ping-pong

  // ---- prologue: load kt=0 into the A set (A first, then B) ----
  #pragma unroll
  for (int s = 0; s < 2; ++s)
    aA[s] = *(const bf16x8*)(aB + s * 512);
  #pragma unroll
  for (int s = 0; s < 2; ++s)
    #pragma unroll
    for (int nt = 0; nt < 4; ++nt)
      bA[s][nt] = *(const bf16x8*)(bB + s * 8192 + nt * 512);

  // ---- K loop: fully unrolled, no barriers, no LDS ----
  #pragma unroll
  for (int kt = 0; kt < NKT; ++kt) {
    const int kn = (kt + 1 < NKT) ? kt + 1 : NKT - 1;   // clamped (dead ok)
    // prefetch kt+1 into the other set: A first, then B (consume order)
    if (kt & 1) {
      #pragma unroll
      for (int s = 0; s < 2; ++s)
        aA[s] = *(const bf16x8*)(aB + kn * 1024 + s * 512);
      #pragma unroll
      for (int s = 0; s < 2; ++s)
        #pragma unroll
        for (int nt = 0; nt < 4; ++nt)
          bA[s][nt] = *(const bf16x8*)(bB + (size_t)kn * 16384 + s * 8192 +
                                       nt * 512);
      // consume the S set (kt odd)
      #pragma unroll
      for (int s = 0; s < 2; ++s)
        #pragma unroll
        for (int nt = 0; nt < 4; ++nt)
          acc[nt] = __builtin_amdgcn_mfma_f32_32x32x16_bf16(
              aS[s], bS[s][nt], acc[nt], 0, 0, 0);
    } else {
      #pragma unroll
      for (int s = 0; s < 2; ++s)
        aS[s] = *(const bf16x8*)(aB + kn * 1024 + s * 512);
      #pragma unroll
      for (int s = 0; s < 2; ++s)
        #pragma unroll
        for (int nt = 0; nt < 4; ++nt)
          bS[s][nt] = *(const bf16x8*)(bB + (size_t)kn * 16384 + s * 8192 +
                                       nt * 512);
      // consume the A set (kt even)
      #pragma unroll
      for (int s = 0; s < 2; ++s)
        #pragma unroll
        for (int nt = 0; nt < 4; ++nt)
          acc[nt] = __builtin_amdgcn_mfma_f32_32x32x16_bf16(
              aA[s], bA[s][nt], acc[nt], 0, 0, 0);
    }
  }

  // ---- epilogue ----
  const float x2v = x2g[row0 + l31];   // lane l31 holds x2(row l31)
  float c2v[4];
  #pragma unroll
  for (int nt = 0; nt < 4; ++nt) c2v[nt] = c2g[wn * 128 + nt * 32 + l31];

  float srow[16];
  #pragma unroll
  for (int r = 0; r < 16; ++r) {
    const int mloc = (r & 3) + 8 * (r >> 2) + 4 * h;   // 0..31
    const float x2m = __shfl(x2v, mloc, 64);
    float s = 0.f;
    #pragma unroll
    for (int nt = 0; nt < 4; ++nt) {
      float d2 = fmaxf(x2m + c2v[nt] - 2.f * acc[nt][r], 0.f);
      float q = __builtin_amdgcn_rcpf(1.f + d2);
      acc[nt][r] = q;
      s += q;
    }
    #pragma unroll
    for (int msk = 1; msk < 32; msk <<= 1) s += __shfl_xor(s, msk, 64);
    srow[r] = s;
  }

  if (l31 == 0) {
    #pragma unroll
    for (int r = 0; r < 16; ++r)
      part[wn][(r & 3) + 8 * (r >> 2) + 4 * h] = srow[r];
  }
  __syncthreads();
  if (tid < BM)
    rowinv[tid] = __builtin_amdgcn_rcpf(part[0][tid] + part[1][tid] +
                                        part[2][tid] + part[3][tid]);
  __syncthreads();

  #pragma unroll
  for (int r = 0; r < 16; ++r) {
    const int row = (r & 3) + 8 * (r >> 2) + 4 * h;
    const float iv = rowinv[row];
    float* o = out + (size_t)(row0 + row) * KC + wn * 128 + l31;
    #pragma unroll
    for (int nt = 0; nt < 4; ++nt)
      o[nt * 32] = acc[nt][r] * iv;
  }
}

extern "C" void kernel_launch(void* const* d_in, const int* in_sizes, int n_in,
                              void* d_out, int out_size, void* d_ws, size_t ws_size,
                              hipStream_t stream) {
  const float* X = (const float*)d_in[0];   // inputs  [131072, 512] fp32
  const float* C = (const float*)d_in[1];   // clusters [512, 512] fp32
  float* out = (float*)d_out;               // [131072, 512] fp32

  // ws layout (as R9, demonstrated sufficient): [Bp 512K][c2][x2g][Xp 128M]
  char* ws = (char*)d_ws;
  short* Bp  = (short*)ws;
  float* c2  = (float*)(ws + (size_t)KC * DIM * 2);
  float* x2g = (float*)(ws + (size_t)KC * DIM * 2 + 4096);
  short* Xp  = (short*)(ws + (1u << 21));

  dec_pack<<<KC, 64, 0, stream>>>(C, Bp, c2);
  dec_packx<<<NPTS / 128, 256, 0, stream>>>(X, Xp, x2g);
  dec_main2<<<NPTS / BM, 256, 0, stream>>>(Xp, Bp, c2, x2g, out);
}